// Round 14
// baseline (47.081 us; speedup 1.0000x reference)
//
#include <hip/hip_runtime.h>
#include <hip/hip_fp16.h>
#include <math.h>

constexpr int D    = 1024;
constexpr int NEXP = 4;
constexpr int EPP  = 2048;
constexpr int CSTR = 16;     // counter padding (64B)

typedef _Float16 f16x8 __attribute__((ext_vector_type(8)));
typedef float    f32x4 __attribute__((ext_vector_type(4)));

__device__ __forceinline__ unsigned pk2(float a, float b) {
    return __builtin_bit_cast(unsigned, __builtin_amdgcn_cvt_pkrtz(a, b));
}
__device__ __forceinline__ f16x8 cvt8(const float* p) {
    const float4 u = *reinterpret_cast<const float4*>(p);
    const float4 v = *reinterpret_cast<const float4*>(p + 4);
    const uint4 w = make_uint4(pk2(u.x, u.y), pk2(u.z, u.w), pk2(v.x, v.y), pk2(v.z, v.w));
    return __builtin_bit_cast(f16x8, w);
}

// ---------------- K1: prep (blocks 0..63) + router-grouping (blocks 64..) ----------------
__global__ __launch_bounds__(256) void prep_router_kernel(
    const float* __restrict__ h, const float* __restrict__ lts,
    const float* __restrict__ Wr, const float* __restrict__ br,
    float* __restrict__ out_ew, int* __restrict__ gcnt, int* __restrict__ list,
    _Float16* __restrict__ lts16, _Float16* __restrict__ ltsT, int ntok)
{
    const int tid = threadIdx.x;

    if (blockIdx.x < 64) {
        // ---- prep: f16 slice copies (verified) ----
        const int e = blockIdx.x >> 4, part = (blockIdx.x >> 2) & 3, dc = blockIdx.x & 3;
        __shared__ __align__(16) _Float16 s[8][256];

        const float4* src = reinterpret_cast<const float4*>(lts);
        #pragma unroll
        for (int i = 0; i < 2; ++i) {
            const int f = tid + 256 * i;
            const int r = f >> 6, c4 = f & 63;
            const float4 v = src[(size_t)(e * EPP + part * 8 + r) * 256 + dc * 64 + c4];
            *reinterpret_cast<uint2*>(&s[r][c4 * 4]) = make_uint2(pk2(v.x, v.y), pk2(v.z, v.w));
        }
        __syncthreads();

        {   // row-major copy
            const int r = tid >> 5, c = tid & 31;
            *reinterpret_cast<uint4*>(lts16 + (size_t)(e * 32 + part * 8 + r) * D + dc * 256 + c * 8) =
                *reinterpret_cast<const uint4*>(&s[r][c * 8]);
        }
        {   // transposed copy
            _Float16 tmp[8];
            #pragma unroll
            for (int k = 0; k < 8; ++k) tmp[k] = s[k][tid];
            *reinterpret_cast<uint4*>(ltsT + ((size_t)e << 15) + (size_t)(dc * 256 + tid) * 32 + part * 8) =
                *reinterpret_cast<const uint4*>(tmp);
        }
        return;
    }

    // ---- router + grouping: 16 tokens per block (4 seq per wave) ----
    const int wid = tid >> 6, lane = tid & 63;
    const int blk = blockIdx.x - 64;

    __shared__ int lds_cnt[NEXP];
    __shared__ int lds_base[NEXP];
    if (tid < NEXP) lds_cnt[tid] = 0;
    __syncthreads();

    const float4* h4 = reinterpret_cast<const float4*>(h);
    const float4* w4 = reinterpret_cast<const float4*>(Wr);
    float4 wf[NEXP][4];
    #pragma unroll
    for (int e2 = 0; e2 < NEXP; ++e2)
        #pragma unroll
        for (int i = 0; i < 4; ++i)
            wf[e2][i] = w4[e2 * 256 + lane + 64 * i];
    const float bb0 = br[0], bb1 = br[1], bb2 = br[2], bb3 = br[3];

    int mybi[4], myrank[4], mytok[4];
    #pragma unroll
    for (int t = 0; t < 4; ++t) {
        const int tok = blk * 16 + wid * 4 + t;
        mytok[t] = -1;
        if (tok < ntok) {
            float acc[NEXP] = {0.f, 0.f, 0.f, 0.f};
            #pragma unroll
            for (int i = 0; i < 4; ++i) {
                const float4 a = h4[(size_t)tok * 256 + lane + 64 * i];
                #pragma unroll
                for (int e2 = 0; e2 < NEXP; ++e2)
                    acc[e2] += a.x * wf[e2][i].x + a.y * wf[e2][i].y
                             + a.z * wf[e2][i].z + a.w * wf[e2][i].w;
            }
            #pragma unroll
            for (int m = 1; m < 64; m <<= 1)
                #pragma unroll
                for (int e2 = 0; e2 < NEXP; ++e2) acc[e2] += __shfl_xor(acc[e2], m);

            const float l0 = acc[0] + bb0, l1 = acc[1] + bb1,
                        l2 = acc[2] + bb2, l3 = acc[3] + bb3;
            const float lm = fmaxf(fmaxf(l0, l1), fmaxf(l2, l3));
            const float e0 = __expf(l0 - lm), e1 = __expf(l1 - lm),
                        e2v = __expf(l2 - lm), e3 = __expf(l3 - lm);
            const float einv = 1.f / (e0 + e1 + e2v + e3);
            if (lane < NEXP) {
                const float ev = (lane == 0) ? e0 : (lane == 1) ? e1 : (lane == 2) ? e2v : e3;
                out_ew[(size_t)tok * NEXP + lane] = ev * einv;
            }
            int bi = 0; float bv = l0;
            if (l1 > bv) { bv = l1; bi = 1; }
            if (l2 > bv) { bv = l2; bi = 2; }
            if (l3 > bv) { bv = l3; bi = 3; }
            if (lane == 0) {
                mytok[t] = tok; mybi[t] = bi;
                myrank[t] = atomicAdd(&lds_cnt[bi], 1);
            }
        }
    }
    __syncthreads();
    if (tid < NEXP) lds_base[tid] = atomicAdd(&gcnt[tid * CSTR], lds_cnt[tid]);
    __syncthreads();
    #pragma unroll
    for (int t = 0; t < 4; ++t)
        if (lane == 0 && mytok[t] >= 0)
            list[(size_t)mybi[t] * ntok + lds_base[mybi[t]] + myrank[t]] = mytok[t];
}

// ---------------- K2: grouped qk + softmax + pv ----------------
// Block (e, tile): 16 tokens, ALL routed to e. Verified QK (K-split waves,
// LDS reduce) + softmax + PV. Inactive tiles exit instantly.
__global__ __launch_bounds__(256) void qkpv_kernel(
    const float* __restrict__ h, const _Float16* __restrict__ lts16,
    const _Float16* __restrict__ ltsT, const int* __restrict__ gcnt,
    const int* __restrict__ list, float* __restrict__ out_res,
    int ntok, int tiles_pe)
{
    const int e    = blockIdx.x / tiles_pe;
    const int tile = blockIdx.x - e * tiles_pe;
    const int n_e  = gcnt[e * CSTR];
    const int base = tile * 16;
    if (base >= n_e) return;                 // uniform per block, before barriers

    const int tid = threadIdx.x, wid = tid >> 6, lane = tid & 63;
    __shared__ int toks[16];
    __shared__ float S_part[4][16][33];      // 8.25 KB
    __shared__ __align__(16) _Float16 P[16][32];

    if (tid < 16) {
        const int idx = base + tid;
        toks[tid] = list[(size_t)e * ntok + (idx < n_e ? idx : n_e - 1)];
    }
    __syncthreads();

    const int rA = lane & 15, g4 = lane >> 4;
    const float*    ap  = h     + (size_t)toks[rA] * D + g4 * 8;
    const _Float16* b0p = lts16 + (size_t)(e * 32 + rA) * D + g4 * 8;
    const _Float16* b1p = b0p + 16 * D;

    // ---- QK: wave wid covers kc in [wid*8, wid*8+8) ----
    f32x4 s0 = {0.f, 0.f, 0.f, 0.f}, s1 = {0.f, 0.f, 0.f, 0.f};
    #pragma unroll
    for (int k = 0; k < 8; ++k) {
        const int kc = wid * 8 + k;
        const f16x8 a  = cvt8(ap + kc * 32);
        const f16x8 b0 = *reinterpret_cast<const f16x8*>(b0p + kc * 32);
        const f16x8 b1 = *reinterpret_cast<const f16x8*>(b1p + kc * 32);
        s0 = __builtin_amdgcn_mfma_f32_16x16x32_f16(a, b0, s0, 0, 0, 0);
        s1 = __builtin_amdgcn_mfma_f32_16x16x32_f16(a, b1, s1, 0, 0, 0);
    }
    #pragma unroll
    for (int r = 0; r < 4; ++r) {
        S_part[wid][g4 * 4 + r][rA]      = s0[r];
        S_part[wid][g4 * 4 + r][rA + 16] = s1[r];
    }
    __syncthreads();

    // ---- reduce + softmax: thread -> (token tr, cols sl & sl+16) ----
    {
        const int tr = tid >> 4, sl = tid & 15;
        const float v0 = S_part[0][tr][sl] + S_part[1][tr][sl]
                       + S_part[2][tr][sl] + S_part[3][tr][sl];
        const float v1 = S_part[0][tr][sl + 16] + S_part[1][tr][sl + 16]
                       + S_part[2][tr][sl + 16] + S_part[3][tr][sl + 16];
        constexpr float inv32 = 1.f / 32.f;  // 1/sqrt(1024)
        float mx = fmaxf(v0, v1);
        #pragma unroll
        for (int m = 1; m < 16; m <<= 1) mx = fmaxf(mx, __shfl_xor(mx, m));
        const float p0 = __expf((v0 - mx) * inv32);
        const float p1 = __expf((v1 - mx) * inv32);
        float sm = p0 + p1;
        #pragma unroll
        for (int m = 1; m < 16; m <<= 1) sm += __shfl_xor(sm, m);
        const float is = 1.f / sm;
        P[tr][sl]      = (_Float16)(p0 * is);
        P[tr][sl + 16] = (_Float16)(p1 * is);
    }
    __syncthreads();

    // ---- PV: wave wid owns dims [wid*256, wid*256+256) ----
    const f16x8 pa = *reinterpret_cast<const f16x8*>(&P[rA][g4 * 8]);
    const _Float16* vtE = ltsT + ((size_t)e << 15);

    #pragma unroll
    for (int i = 0; i < 16; ++i) {
        const int dimc = wid * 256 + i * 16 + rA;
        const f16x8 bk = *reinterpret_cast<const f16x8*>(vtE + (size_t)dimc * 32 + g4 * 8);
        f32x4 o = {0.f, 0.f, 0.f, 0.f};
        o = __builtin_amdgcn_mfma_f32_16x16x32_f16(pa, bk, o, 0, 0, 0);
        #pragma unroll
        for (int r = 0; r < 4; ++r) {
            const int tr2 = g4 * 4 + r;
            if (base + tr2 < n_e)
                out_res[(size_t)toks[tr2] * D + dimc] = o[r];
        }
    }
}

extern "C" void kernel_launch(void* const* d_in, const int* in_sizes, int n_in,
                              void* d_out, int out_size, void* d_ws, size_t ws_size,
                              hipStream_t stream) {
    const float* h   = (const float*)d_in[0];
    const float* lts = (const float*)d_in[1];
    const float* Wr  = (const float*)d_in[2];
    const float* br  = (const float*)d_in[3];

    const int ntok = in_sizes[0] / D;            // b*t = 4096
    float* out_res = (float*)d_out;              // (b,t,d)
    float* out_ew  = out_res + (size_t)ntok * D; // (b,t,NEXP)

    _Float16* lts16 = (_Float16*)d_ws;                    // 128x1024 (256 KB)
    _Float16* ltsT  = lts16 + (size_t)128 * D;            // 4x1024x32 (256 KB)
    int* gcnt = (int*)(ltsT + (size_t)NEXP * D * 32);     // NEXP*CSTR padded
    int* list = gcnt + NEXP * CSTR;                       // [NEXP][ntok]

    (void)hipMemsetAsync(gcnt, 0, NEXP * CSTR * sizeof(int), stream);

    const int rblocks = (ntok + 15) / 16;        // 256
    prep_router_kernel<<<64 + rblocks, 256, 0, stream>>>(h, lts, Wr, br, out_ew,
                                                         gcnt, list, lts16, ltsT, ntok);

    const int tiles_pe = (ntok + 15) / 16;       // 256 (covers worst-case skew)
    qkpv_kernel<<<NEXP * tiles_pe, 256, 0, stream>>>(h, lts16, ltsT, gcnt, list,
                                                     out_res, ntok, tiles_pe);
}

// Round 15
// 46.057 us; speedup vs baseline: 1.0222x; 1.0222x over previous
//
#include <hip/hip_runtime.h>
#include <hip/hip_fp16.h>
#include <math.h>

constexpr int D    = 1024;
constexpr int NEXP = 4;
constexpr int EPP  = 2048;
constexpr int CSTR = 16;     // counter padding (64B)

typedef _Float16 f16x8 __attribute__((ext_vector_type(8)));
typedef float    f32x4 __attribute__((ext_vector_type(4)));

__device__ __forceinline__ unsigned pk2(float a, float b) {
    return __builtin_bit_cast(unsigned, __builtin_amdgcn_cvt_pkrtz(a, b));
}
__device__ __forceinline__ f16x8 cvt8(const float* p) {
    const float4 u = *reinterpret_cast<const float4*>(p);
    const float4 v = *reinterpret_cast<const float4*>(p + 4);
    const uint4 w = make_uint4(pk2(u.x, u.y), pk2(u.z, u.w), pk2(v.x, v.y), pk2(v.z, v.w));
    return __builtin_bit_cast(f16x8, w);
}

// ---------------- K1: 1024-thread blocks. 0..15 = prep; 16.. = router ----------------
// Prep block b2=bid (e=b2>>2, part=b2&3; dc=tid>>8): f16 slice copies.
// Router: 1 token per wave (16/block), LDS-aggregated grouping atomics.
__global__ __launch_bounds__(1024) void prep_router_kernel(
    const float* __restrict__ h, const float* __restrict__ lts,
    const float* __restrict__ Wr, const float* __restrict__ br,
    float* __restrict__ out_ew, int* __restrict__ gcnt, int* __restrict__ list,
    _Float16* __restrict__ lts16, _Float16* __restrict__ ltsT, int ntok)
{
    const int tid = threadIdx.x;

    if (blockIdx.x < 16) {
        const int e = blockIdx.x >> 2, part = blockIdx.x & 3;
        const int dc = tid >> 8, t256 = tid & 255;
        __shared__ __align__(16) _Float16 s[4][8][256];   // 16 KB

        const float4* src = reinterpret_cast<const float4*>(lts);
        #pragma unroll
        for (int i = 0; i < 2; ++i) {
            const int f = t256 + 256 * i;
            const int r = f >> 6, c4 = f & 63;
            const float4 v = src[(size_t)(e * EPP + part * 8 + r) * 256 + dc * 64 + c4];
            *reinterpret_cast<uint2*>(&s[dc][r][c4 * 4]) =
                make_uint2(pk2(v.x, v.y), pk2(v.z, v.w));
        }
        __syncthreads();

        {   // row-major copy
            const int r = t256 >> 5, c = t256 & 31;
            *reinterpret_cast<uint4*>(lts16 + (size_t)(e * 32 + part * 8 + r) * D + dc * 256 + c * 8) =
                *reinterpret_cast<const uint4*>(&s[dc][r][c * 8]);
        }
        {   // transposed copy
            _Float16 tmp[8];
            #pragma unroll
            for (int k = 0; k < 8; ++k) tmp[k] = s[dc][k][t256];
            *reinterpret_cast<uint4*>(ltsT + ((size_t)e << 15) + (size_t)(dc * 256 + t256) * 32 + part * 8) =
                *reinterpret_cast<const uint4*>(tmp);
        }
        return;
    }

    // ---- router: 16 waves, 1 token each ----
    const int wid = tid >> 6, lane = tid & 63;
    const int tok = (blockIdx.x - 16) * 16 + wid;

    __shared__ int lds_cnt[NEXP];
    __shared__ int lds_base[NEXP];
    if (tid < NEXP) lds_cnt[tid] = 0;
    __syncthreads();

    int mybi = -1, myrank = 0;
    if (tok < ntok) {
        const float4* h4 = reinterpret_cast<const float4*>(h);
        const float4* w4 = reinterpret_cast<const float4*>(Wr);
        float acc[NEXP] = {0.f, 0.f, 0.f, 0.f};
        #pragma unroll
        for (int i = 0; i < 4; ++i) {
            const float4 a = h4[(size_t)tok * 256 + lane + 64 * i];
            #pragma unroll
            for (int e = 0; e < NEXP; ++e) {
                const float4 w = w4[e * 256 + lane + 64 * i];
                acc[e] += a.x * w.x + a.y * w.y + a.z * w.z + a.w * w.w;
            }
        }
        #pragma unroll
        for (int m = 1; m < 64; m <<= 1)
            #pragma unroll
            for (int e = 0; e < NEXP; ++e) acc[e] += __shfl_xor(acc[e], m);

        const float l0 = acc[0] + br[0], l1 = acc[1] + br[1],
                    l2 = acc[2] + br[2], l3 = acc[3] + br[3];
        const float lm = fmaxf(fmaxf(l0, l1), fmaxf(l2, l3));
        const float e0 = __expf(l0 - lm), e1 = __expf(l1 - lm),
                    e2 = __expf(l2 - lm), e3 = __expf(l3 - lm);
        const float einv = 1.f / (e0 + e1 + e2 + e3);
        if (lane < NEXP) {
            const float ev = (lane == 0) ? e0 : (lane == 1) ? e1 : (lane == 2) ? e2 : e3;
            out_ew[(size_t)tok * NEXP + lane] = ev * einv;
        }
        int bi = 0; float bv = l0;
        if (l1 > bv) { bv = l1; bi = 1; }
        if (l2 > bv) { bv = l2; bi = 2; }
        if (l3 > bv) { bv = l3; bi = 3; }
        if (lane == 0) {
            mybi = bi;
            myrank = atomicAdd(&lds_cnt[bi], 1);
        }
    }
    __syncthreads();
    if (tid < NEXP) lds_base[tid] = atomicAdd(&gcnt[tid * CSTR], lds_cnt[tid]);
    __syncthreads();
    if (mybi >= 0 && lane == 0)
        list[(size_t)mybi * ntok + lds_base[mybi] + myrank] = tok;
}

// ---------------- K2: grouped qk + softmax + pv (verified R14 body) ----------------
__global__ __launch_bounds__(256) void qkpv_kernel(
    const float* __restrict__ h, const _Float16* __restrict__ lts16,
    const _Float16* __restrict__ ltsT, const int* __restrict__ gcnt,
    const int* __restrict__ list, float* __restrict__ out_res,
    int ntok, int tiles_pe)
{
    const int e    = blockIdx.x / tiles_pe;
    const int tile = blockIdx.x - e * tiles_pe;
    const int n_e  = gcnt[e * CSTR];
    const int base = tile * 16;
    if (base >= n_e) return;                 // uniform per block, before barriers

    const int tid = threadIdx.x, wid = tid >> 6, lane = tid & 63;
    __shared__ int toks[16];
    __shared__ float S_part[4][16][33];      // 8.25 KB
    __shared__ __align__(16) _Float16 P[16][32];

    if (tid < 16) {
        const int idx = base + tid;
        toks[tid] = list[(size_t)e * ntok + (idx < n_e ? idx : n_e - 1)];
    }
    __syncthreads();

    const int rA = lane & 15, g4 = lane >> 4;
    const float*    ap  = h     + (size_t)toks[rA] * D + g4 * 8;
    const _Float16* b0p = lts16 + (size_t)(e * 32 + rA) * D + g4 * 8;
    const _Float16* b1p = b0p + 16 * D;

    // ---- QK: wave wid covers kc in [wid*8, wid*8+8) ----
    f32x4 s0 = {0.f, 0.f, 0.f, 0.f}, s1 = {0.f, 0.f, 0.f, 0.f};
    #pragma unroll
    for (int k = 0; k < 8; ++k) {
        const int kc = wid * 8 + k;
        const f16x8 a  = cvt8(ap + kc * 32);
        const f16x8 b0 = *reinterpret_cast<const f16x8*>(b0p + kc * 32);
        const f16x8 b1 = *reinterpret_cast<const f16x8*>(b1p + kc * 32);
        s0 = __builtin_amdgcn_mfma_f32_16x16x32_f16(a, b0, s0, 0, 0, 0);
        s1 = __builtin_amdgcn_mfma_f32_16x16x32_f16(a, b1, s1, 0, 0, 0);
    }
    #pragma unroll
    for (int r = 0; r < 4; ++r) {
        S_part[wid][g4 * 4 + r][rA]      = s0[r];
        S_part[wid][g4 * 4 + r][rA + 16] = s1[r];
    }
    __syncthreads();

    // ---- reduce + softmax ----
    {
        const int tr = tid >> 4, sl = tid & 15;
        const float v0 = S_part[0][tr][sl] + S_part[1][tr][sl]
                       + S_part[2][tr][sl] + S_part[3][tr][sl];
        const float v1 = S_part[0][tr][sl + 16] + S_part[1][tr][sl + 16]
                       + S_part[2][tr][sl + 16] + S_part[3][tr][sl + 16];
        constexpr float inv32 = 1.f / 32.f;  // 1/sqrt(1024)
        float mx = fmaxf(v0, v1);
        #pragma unroll
        for (int m = 1; m < 16; m <<= 1) mx = fmaxf(mx, __shfl_xor(mx, m));
        const float p0 = __expf((v0 - mx) * inv32);
        const float p1 = __expf((v1 - mx) * inv32);
        float sm = p0 + p1;
        #pragma unroll
        for (int m = 1; m < 16; m <<= 1) sm += __shfl_xor(sm, m);
        const float is = 1.f / sm;
        P[tr][sl]      = (_Float16)(p0 * is);
        P[tr][sl + 16] = (_Float16)(p1 * is);
    }
    __syncthreads();

    // ---- PV: wave wid owns dims [wid*256, wid*256+256) ----
    const f16x8 pa = *reinterpret_cast<const f16x8*>(&P[rA][g4 * 8]);
    const _Float16* vtE = ltsT + ((size_t)e << 15);

    #pragma unroll
    for (int i = 0; i < 16; ++i) {
        const int dimc = wid * 256 + i * 16 + rA;
        const f16x8 bk = *reinterpret_cast<const f16x8*>(vtE + (size_t)dimc * 32 + g4 * 8);
        f32x4 o = {0.f, 0.f, 0.f, 0.f};
        o = __builtin_amdgcn_mfma_f32_16x16x32_f16(pa, bk, o, 0, 0, 0);
        #pragma unroll
        for (int r = 0; r < 4; ++r) {
            const int tr2 = g4 * 4 + r;
            if (base + tr2 < n_e)
                out_res[(size_t)toks[tr2] * D + dimc] = o[r];
        }
    }
}

extern "C" void kernel_launch(void* const* d_in, const int* in_sizes, int n_in,
                              void* d_out, int out_size, void* d_ws, size_t ws_size,
                              hipStream_t stream) {
    const float* h   = (const float*)d_in[0];
    const float* lts = (const float*)d_in[1];
    const float* Wr  = (const float*)d_in[2];
    const float* br  = (const float*)d_in[3];

    const int ntok = in_sizes[0] / D;            // b*t = 4096
    float* out_res = (float*)d_out;              // (b,t,d)
    float* out_ew  = out_res + (size_t)ntok * D; // (b,t,NEXP)

    _Float16* lts16 = (_Float16*)d_ws;                    // 128x1024 (256 KB)
    _Float16* ltsT  = lts16 + (size_t)128 * D;            // 4x1024x32 (256 KB)
    int* gcnt = (int*)(ltsT + (size_t)NEXP * D * 32);     // NEXP*CSTR padded
    int* list = gcnt + NEXP * CSTR;                       // [NEXP][ntok]

    (void)hipMemsetAsync(gcnt, 0, NEXP * CSTR * sizeof(int), stream);

    const int rblocks = 16 + (ntok + 15) / 16;   // 16 prep + 256 router
    prep_router_kernel<<<rblocks, 1024, 0, stream>>>(h, lts, Wr, br, out_ew,
                                                     gcnt, list, lts16, ltsT, ntok);

    const int tiles_pe = (ntok + 15) / 16;       // 256 (covers worst-case skew)
    qkpv_kernel<<<NEXP * tiles_pe, 256, 0, stream>>>(h, lts16, ltsT, gcnt, list,
                                                     out_res, ntok, tiles_pe);
}

// Round 17
// 35.472 us; speedup vs baseline: 1.3273x; 1.2984x over previous
//
#include <hip/hip_runtime.h>
#include <hip/hip_fp16.h>
#include <math.h>

constexpr int D    = 1024;
constexpr int NEXP = 4;
constexpr int EPP  = 2048;

typedef _Float16 f16x8 __attribute__((ext_vector_type(8)));
typedef float    f32x4 __attribute__((ext_vector_type(4)));

__device__ __forceinline__ unsigned pk2(float a, float b) {
    return __builtin_bit_cast(unsigned, __builtin_amdgcn_cvt_pkrtz(a, b));
}

// ---------------- K1: prep (blocks 0..63) + router (blocks 64..) ----------------
__global__ __launch_bounds__(256) void prep_router_kernel(
    const float* __restrict__ h, const float* __restrict__ lts,
    const float* __restrict__ Wr, const float* __restrict__ br,
    float* __restrict__ out_ew, int* __restrict__ eidx,
    _Float16* __restrict__ h16, _Float16* __restrict__ lts16,
    _Float16* __restrict__ ltsT, int ntok)
{
    const int tid = threadIdx.x;

    if (blockIdx.x < 64) {
        // ---- prep: f16 slice copies ----
        const int e = blockIdx.x >> 4, part = (blockIdx.x >> 2) & 3, dc = blockIdx.x & 3;
        __shared__ __align__(16) _Float16 s[8][256];

        const float4* src = reinterpret_cast<const float4*>(lts);
        #pragma unroll
        for (int i = 0; i < 2; ++i) {
            const int f = tid + 256 * i;
            const int r = f >> 6, c4 = f & 63;
            const float4 v = src[(size_t)(e * EPP + part * 8 + r) * 256 + dc * 64 + c4];
            *reinterpret_cast<uint2*>(&s[r][c4 * 4]) = make_uint2(pk2(v.x, v.y), pk2(v.z, v.w));
        }
        __syncthreads();

        {   // row-major copy
            const int r = tid >> 5, c = tid & 31;
            *reinterpret_cast<uint4*>(lts16 + (size_t)(e * 32 + part * 8 + r) * D + dc * 256 + c * 8) =
                *reinterpret_cast<const uint4*>(&s[r][c * 8]);
        }
        {   // transposed copy
            _Float16 tmp[8];
            #pragma unroll
            for (int k = 0; k < 8; ++k) tmp[k] = s[k][tid];
            *reinterpret_cast<uint4*>(ltsT + ((size_t)e << 15) + (size_t)(dc * 256 + tid) * 32 + part * 8) =
                *reinterpret_cast<const uint4*>(tmp);
        }
        return;
    }

    // ---- router: 1 token per wave ----
    const int wid = tid >> 6, lane = tid & 63;
    const int tok = (blockIdx.x - 64) * 4 + wid;
    if (tok >= ntok) return;

    const float4* h4 = reinterpret_cast<const float4*>(h);
    const float4* w4 = reinterpret_cast<const float4*>(Wr);

    float4 av[4];
    float acc[NEXP] = {0.f, 0.f, 0.f, 0.f};
    #pragma unroll
    for (int i = 0; i < 4; ++i) {
        av[i] = h4[(size_t)tok * 256 + lane + 64 * i];
        #pragma unroll
        for (int e = 0; e < NEXP; ++e) {
            const float4 w = w4[e * 256 + lane + 64 * i];
            acc[e] += av[i].x * w.x + av[i].y * w.y + av[i].z * w.z + av[i].w * w.w;
        }
    }
    #pragma unroll
    for (int m = 1; m < 64; m <<= 1)
        #pragma unroll
        for (int e = 0; e < NEXP; ++e) acc[e] += __shfl_xor(acc[e], m);

    const float l0 = acc[0] + br[0], l1 = acc[1] + br[1],
                l2 = acc[2] + br[2], l3 = acc[3] + br[3];
    const float lm = fmaxf(fmaxf(l0, l1), fmaxf(l2, l3));
    const float e0 = __expf(l0 - lm), e1 = __expf(l1 - lm),
                e2 = __expf(l2 - lm), e3 = __expf(l3 - lm);
    const float einv = 1.f / (e0 + e1 + e2 + e3);
    if (lane < NEXP) {
        const float ev = (lane == 0) ? e0 : (lane == 1) ? e1 : (lane == 2) ? e2 : e3;
        out_ew[(size_t)tok * NEXP + lane] = ev * einv;
    }
    int bi = 0; float bv = l0;
    if (l1 > bv) { bv = l1; bi = 1; }
    if (l2 > bv) { bv = l2; bi = 2; }
    if (l3 > bv) { bv = l3; bi = 3; }
    if (lane == 0) eidx[tok] = bi;

    #pragma unroll
    for (int i = 0; i < 4; ++i)
        *reinterpret_cast<uint2*>(h16 + (size_t)tok * D + (lane + 64 * i) * 4) =
            make_uint2(pk2(av[i].x, av[i].y), pk2(av[i].z, av[i].w));
}

// ---------------- K2: qk + softmax + pv for one (expert, 16-token chunk) ----------------
__global__ __launch_bounds__(256) void qkpv_kernel(
    const _Float16* __restrict__ h16, const _Float16* __restrict__ lts16,
    const _Float16* __restrict__ ltsT, const int* __restrict__ eidx,
    float* __restrict__ out_res, int ntok, int chunks)
{
    const int e = blockIdx.x / chunks;
    const int chunk = blockIdx.x - e * chunks;
    const int base = chunk * 16;

    const int tid = threadIdx.x, wid = tid >> 6, lane = tid & 63;
    __shared__ int eix[16];
    __shared__ float S_part[4][16][33];                  // 8.25 KB
    __shared__ __align__(16) _Float16 P[16][32];         // 1 KB

    if (tid < 16) {
        const int tk = base + tid;
        eix[tid] = (tk < ntok) ? eidx[tk] : -1;
    }

    const int rA = lane & 15, g4 = lane >> 4;
    int hr = base + rA; if (hr > ntok - 1) hr = ntok - 1;
    const _Float16* ap  = h16   + (size_t)hr * D + g4 * 8;
    const _Float16* b0p = lts16 + (size_t)(e * 32 + rA) * D + g4 * 8;
    const _Float16* b1p = b0p + 16 * D;

    // ---- QK: wave wid covers kc in [wid*8, wid*8+8) ----
    f32x4 s0 = {0.f, 0.f, 0.f, 0.f}, s1 = {0.f, 0.f, 0.f, 0.f};
    #pragma unroll
    for (int k = 0; k < 8; ++k) {
        const int kc = wid * 8 + k;
        const f16x8 a  = *reinterpret_cast<const f16x8*>(ap  + kc * 32);
        const f16x8 b0 = *reinterpret_cast<const f16x8*>(b0p + kc * 32);
        const f16x8 b1 = *reinterpret_cast<const f16x8*>(b1p + kc * 32);
        s0 = __builtin_amdgcn_mfma_f32_16x16x32_f16(a, b0, s0, 0, 0, 0);
        s1 = __builtin_amdgcn_mfma_f32_16x16x32_f16(a, b1, s1, 0, 0, 0);
    }
    #pragma unroll
    for (int r = 0; r < 4; ++r) {
        S_part[wid][g4 * 4 + r][rA]      = s0[r];
        S_part[wid][g4 * 4 + r][rA + 16] = s1[r];
    }
    __syncthreads();

    // ---- reduce + softmax: thread -> (token tr, cols sl & sl+16) ----
    {
        const int tr = tid >> 4, sl = tid & 15;
        const float v0 = S_part[0][tr][sl] + S_part[1][tr][sl]
                       + S_part[2][tr][sl] + S_part[3][tr][sl];
        const float v1 = S_part[0][tr][sl + 16] + S_part[1][tr][sl + 16]
                       + S_part[2][tr][sl + 16] + S_part[3][tr][sl + 16];
        constexpr float inv32 = 1.f / 32.f;              // 1/sqrt(1024)
        float mx = fmaxf(v0, v1);
        #pragma unroll
        for (int m = 1; m < 16; m <<= 1) mx = fmaxf(mx, __shfl_xor(mx, m));
        const float p0 = __expf((v0 - mx) * inv32);
        const float p1 = __expf((v1 - mx) * inv32);
        float sm = p0 + p1;
        #pragma unroll
        for (int m = 1; m < 16; m <<= 1) sm += __shfl_xor(sm, m);
        const float is = 1.f / sm;
        P[tr][sl]      = (_Float16)(p0 * is);
        P[tr][sl + 16] = (_Float16)(p1 * is);
    }
    __syncthreads();

    // ---- PV: wave wid owns dims [wid*256, wid*256+256) ----
    const f16x8 pa = *reinterpret_cast<const f16x8*>(&P[rA][g4 * 8]);
    const _Float16* vtE = ltsT + ((size_t)e << 15);

    #pragma unroll
    for (int i = 0; i < 16; ++i) {
        const int dimc = wid * 256 + i * 16 + rA;
        const f16x8 bk = *reinterpret_cast<const f16x8*>(vtE + (size_t)dimc * 32 + g4 * 8);
        f32x4 o = {0.f, 0.f, 0.f, 0.f};
        o = __builtin_amdgcn_mfma_f32_16x16x32_f16(pa, bk, o, 0, 0, 0);
        #pragma unroll
        for (int r = 0; r < 4; ++r) {
            const int tr2 = g4 * 4 + r;
            if (base + tr2 < ntok && eix[tr2] == e)
                out_res[(size_t)(base + tr2) * D + dimc] = o[r];
        }
    }
}

extern "C" void kernel_launch(void* const* d_in, const int* in_sizes, int n_in,
                              void* d_out, int out_size, void* d_ws, size_t ws_size,
                              hipStream_t stream) {
    const float* h   = (const float*)d_in[0];
    const float* lts = (const float*)d_in[1];
    const float* Wr  = (const float*)d_in[2];
    const float* br  = (const float*)d_in[3];

    const int ntok = in_sizes[0] / D;            // b*t = 4096
    float* out_res = (float*)d_out;              // (b,t,d)
    float* out_ew  = out_res + (size_t)ntok * D; // (b,t,NEXP)

    _Float16* lts16 = (_Float16*)d_ws;                    // 128x1024 (256 KB)
    _Float16* ltsT  = lts16 + (size_t)128 * D;            // 4x1024x32 (256 KB)
    int*      eidx  = (int*)(ltsT + (size_t)NEXP * D * 32);
    _Float16* h16   = (_Float16*)(eidx + ntok);           // ntok x 1024 (8 MB)

    const int chunks = (ntok + 15) / 16;         // 256

    const int rblocks = 64 + (ntok + 3) / 4;     // 64 prep + 1024 router
    prep_router_kernel<<<rblocks, 256, 0, stream>>>(h, lts, Wr, br, out_ew, eidx,
                                                    h16, lts16, ltsT, ntok);
    qkpv_kernel<<<NEXP * chunks, 256, 0, stream>>>(h16, lts16, ltsT, eidx,
                                                   out_res, ntok, chunks);
}